// Round 1
// baseline (4495.330 us; speedup 1.0000x reference)
//
#include <hip/hip_runtime.h>
#include <cstdint>
#include <cmath>

// Problem constants: B=8, x reshaped (8,15,512,512) fp32.
// gating: conv7x7 s2 p3 (15->64, 256x256) -> BN -> relu -> maxpool3x3 s2 p1 (128x128)
//         -> mean -> FC(64->3) -> top-1
// expert (selected per batch): conv7x7 s2 p3 (15->64) relu -> conv3x3 s2 p1 (64->128) relu
//         -> conv3x3 s1 p1 (128->128)+b relu -> conv1x1 (128->5)+b
// out: hm(8,1,128,128) | wh(8,2,128,128) | reg(8,2,128,128) | 0.01*aux  = 655361 floats

// ---------------- conv 7x7 stride2 pad3, Cin=15, Cout=64, 512->256 ----------------
// MODE 0: gating weights + BN + relu. MODE 1: per-batch expert weights + relu.
template<int MODE>
__global__ __launch_bounds__(256) void conv7_k(
    const float* __restrict__ in, const float* __restrict__ w,
    const float* __restrict__ bn_g, const float* __restrict__ bn_b,
    const float* __restrict__ bn_m, const float* __restrict__ bn_v,
    const int* __restrict__ sel, float* __restrict__ out)
{
  constexpr int IW = 69, IH = 21;
  __shared__ float s_in[IH * IW];
  const int bid = blockIdx.x;
  const int xt = bid & 7;          // 8 x-tiles of 32
  const int yt = (bid >> 3) & 31;  // 32 y-tiles of 8
  const int cb = (bid >> 8) & 1;   // 2 cout halves of 32
  const int b  = bid >> 9;         // 8 batches
  const int tid = threadIdx.x;
  const int tx = tid & 31, ty = tid >> 5;
  const int ox = xt * 32 + tx, oy = yt * 8 + ty;
  const int ix0 = xt * 64 - 3, iy0 = yt * 16 - 3;

  const float* wbase;
  if constexpr (MODE == 0) {
    wbase = w + (size_t)(cb * 32) * (15 * 49);
  } else {
    const int e = sel[b];
    wbase = w + ((size_t)e * 64 + cb * 32) * (15 * 49);
  }
  const float* inb = in + (size_t)b * (15 * 512 * 512);

  float acc[32];
#pragma unroll
  for (int i = 0; i < 32; ++i) acc[i] = 0.f;

#pragma unroll 1
  for (int cin = 0; cin < 15; ++cin) {
    __syncthreads();
    const float* ip = inb + (size_t)cin * (512 * 512);
    for (int i = tid; i < IH * IW; i += 256) {
      const int r = i / IW, c = i - r * IW;
      const int gy = iy0 + r, gx = ix0 + c;
      float v = 0.f;
      if ((unsigned)gy < 512u && (unsigned)gx < 512u) v = ip[gy * 512 + gx];
      s_in[i] = v;
    }
    __syncthreads();
    float v[49];
#pragma unroll
    for (int ky = 0; ky < 7; ++ky)
#pragma unroll
      for (int kx = 0; kx < 7; ++kx)
        v[ky * 7 + kx] = s_in[(2 * ty + ky) * IW + (2 * tx + kx)];
    const float* wcin = wbase + cin * 49;
#pragma unroll
    for (int co = 0; co < 32; ++co) {
      const float* wc = wcin + (size_t)co * (15 * 49);
#pragma unroll
      for (int k = 0; k < 49; ++k) acc[co] = fmaf(wc[k], v[k], acc[co]);
    }
  }

  const size_t obase = (((size_t)b * 64 + cb * 32) * 65536) + (size_t)(oy * 256 + ox);
#pragma unroll
  for (int co = 0; co < 32; ++co) {
    float r = acc[co];
    if constexpr (MODE == 0) {
      const int c = cb * 32 + co;
      const float sc = bn_g[c] * rsqrtf(bn_v[c] + 1e-5f);
      r = r * sc + (bn_b[c] - bn_m[c] * sc);
    }
    r = fmaxf(r, 0.f);
    out[obase + (size_t)co * 65536] = r;
  }
}

// ---------------- maxpool 3x3 s2 p1 (256->128) + spatial mean ----------------
__global__ __launch_bounds__(256) void pool_mean_k(
    const float* __restrict__ f, float* __restrict__ pooled)
{
  const int bc = blockIdx.x;  // b*64 + c, 512 blocks
  const float* src = f + (size_t)bc * 65536;
  float sum = 0.f;
  for (int i = threadIdx.x; i < 16384; i += 256) {
    const int ph = i >> 7, pw = i & 127;
    const int y0 = 2 * ph - 1, x0 = 2 * pw - 1;
    float m = -1e30f;
#pragma unroll
    for (int dy = 0; dy < 3; ++dy) {
      const int y = y0 + dy;
      if ((unsigned)y < 256u) {
#pragma unroll
        for (int dx = 0; dx < 3; ++dx) {
          const int x = x0 + dx;
          if ((unsigned)x < 256u) m = fmaxf(m, src[y * 256 + x]);
        }
      }
    }
    sum += m;
  }
  __shared__ float red[4];
#pragma unroll
  for (int off = 32; off > 0; off >>= 1) sum += __shfl_down(sum, off, 64);
  if ((threadIdx.x & 63) == 0) red[threadIdx.x >> 6] = sum;
  __syncthreads();
  if (threadIdx.x == 0)
    pooled[bc] = (red[0] + red[1] + red[2] + red[3]) * (1.f / 16384.f);
}

// ---------------- FC + top-1 + aux loss ----------------
__global__ __launch_bounds__(64) void gate_k(
    const float* __restrict__ pooled, const float* __restrict__ fcw,
    const float* __restrict__ fcb, int* __restrict__ sel, float* __restrict__ out_aux)
{
  __shared__ float probs[8][3];
  __shared__ int sidx[8];
  const int b = threadIdx.x;
  if (b < 8) {
    float l[3];
#pragma unroll
    for (int e = 0; e < 3; ++e) {
      float s = fcb[e];
      for (int c = 0; c < 64; ++c) s = fmaf(pooled[b * 64 + c], fcw[e * 64 + c], s);
      l[e] = s;
    }
    int best = 0;
    if (l[1] > l[best]) best = 1;
    if (l[2] > l[best]) best = 2;
    sel[b] = best;
    sidx[b] = best;
    const float m = fmaxf(l[0], fmaxf(l[1], l[2]));
    const float e0 = expf(l[0] - m), e1 = expf(l[1] - m), e2 = expf(l[2] - m);
    const float inv = 1.f / (e0 + e1 + e2);
    probs[b][0] = e0 * inv; probs[b][1] = e1 * inv; probs[b][2] = e2 * inv;
  }
  __syncthreads();
  if (threadIdx.x == 0) {
    float cnt[3] = {0.f, 0.f, 0.f}, pr[3] = {0.f, 0.f, 0.f};
    for (int bb = 0; bb < 8; ++bb) {
      cnt[sidx[bb]] += 1.f;
#pragma unroll
      for (int e = 0; e < 3; ++e) pr[e] += probs[bb][e];
    }
    float aux = 0.f;
#pragma unroll
    for (int e = 0; e < 3; ++e) aux += (cnt[e] * 0.125f) * (pr[e] * 0.125f);
    *out_aux = 0.01f * (3.f * aux);
  }
}

// ---------------- conv 3x3, Cout=128, per-batch expert weights, relu ----------------
// STRIDE=2: 256->128, CINC=64 (conv2).  STRIDE=1: 128->128, CINC=128, +bias (head1).
template<int STRIDE, int CINC, int INSZ, int OUTSZ, bool HASBIAS>
__global__ __launch_bounds__(256) void conv3_k(
    const float* __restrict__ in, const float* __restrict__ w,
    const float* __restrict__ bias, const int* __restrict__ sel,
    float* __restrict__ out)
{
  constexpr int IW = (STRIDE == 2) ? 65 : 34;
  constexpr int IH = (STRIDE == 2) ? 17 : 10;
  __shared__ float s_in[IH * IW];
  const int bid = blockIdx.x;
  const int xt = bid & 3;          // 4 x-tiles of 32
  const int yt = (bid >> 2) & 15;  // 16 y-tiles of 8
  const int cb = (bid >> 6) & 1;   // 2 cout halves of 64
  const int b  = bid >> 7;         // 8 batches
  const int tid = threadIdx.x;
  const int tx = tid & 31, ty = tid >> 5;
  const int ox = xt * 32 + tx, oy = yt * 8 + ty;
  const int ix0 = (STRIDE == 2) ? (xt * 64 - 1) : (xt * 32 - 1);
  const int iy0 = (STRIDE == 2) ? (yt * 16 - 1) : (yt * 8 - 1);

  const int e = sel[b];
  const float* wbase = w + ((size_t)e * 128 + cb * 64) * (CINC * 9);
  const float* inb = in + (size_t)b * CINC * (INSZ * INSZ);

  float acc[64];
#pragma unroll
  for (int i = 0; i < 64; ++i) acc[i] = 0.f;

#pragma unroll 1
  for (int cin = 0; cin < CINC; ++cin) {
    __syncthreads();
    const float* ip = inb + (size_t)cin * (INSZ * INSZ);
    for (int i = tid; i < IH * IW; i += 256) {
      const int r = i / IW, c = i - r * IW;
      const int gy = iy0 + r, gx = ix0 + c;
      float v = 0.f;
      if ((unsigned)gy < (unsigned)INSZ && (unsigned)gx < (unsigned)INSZ)
        v = ip[gy * INSZ + gx];
      s_in[i] = v;
    }
    __syncthreads();
    float v[9];
#pragma unroll
    for (int ky = 0; ky < 3; ++ky)
#pragma unroll
      for (int kx = 0; kx < 3; ++kx)
        v[ky * 3 + kx] = s_in[(STRIDE * ty + ky) * IW + (STRIDE * tx + kx)];
    const float* wcin = wbase + cin * 9;
#pragma unroll
    for (int co = 0; co < 64; ++co) {
      const float* wc = wcin + (size_t)co * (CINC * 9);
#pragma unroll
      for (int k = 0; k < 9; ++k) acc[co] = fmaf(wc[k], v[k], acc[co]);
    }
  }

  const size_t obase = (((size_t)b * 128 + cb * 64) * (OUTSZ * OUTSZ))
                     + (size_t)(oy * OUTSZ + ox);
#pragma unroll
  for (int co = 0; co < 64; ++co) {
    float r = acc[co];
    if constexpr (HASBIAS) r += bias[e * 128 + cb * 64 + co];
    r = fmaxf(r, 0.f);
    out[obase + (size_t)co * (OUTSZ * OUTSZ)] = r;
  }
}

// ---------------- head 1x1 conv 128->5 + bias, scatter to hm/wh/reg ----------------
__global__ __launch_bounds__(256) void head2_k(
    const float* __restrict__ in, const float* __restrict__ w,
    const float* __restrict__ b2, const int* __restrict__ sel,
    float* __restrict__ out)
{
  const int bid = blockIdx.x;          // 512 = 8 b * 64 pixel-blocks
  const int b = bid >> 6;
  const int p = ((bid & 63) << 8) + threadIdx.x;  // 0..16383
  const int e = sel[b];
  const float* wp = w + (size_t)e * 5 * 128;      // (5,128)
  const float* ip = in + (((size_t)b * 128) << 14) + p;
  float a0 = 0.f, a1 = 0.f, a2 = 0.f, a3 = 0.f, a4 = 0.f;
#pragma unroll 4
  for (int c = 0; c < 128; ++c) {
    const float v = ip[(size_t)c << 14];
    a0 = fmaf(v, wp[c], a0);
    a1 = fmaf(v, wp[128 + c], a1);
    a2 = fmaf(v, wp[256 + c], a2);
    a3 = fmaf(v, wp[384 + c], a3);
    a4 = fmaf(v, wp[512 + c], a4);
  }
  a0 += b2[e * 5 + 0]; a1 += b2[e * 5 + 1]; a2 += b2[e * 5 + 2];
  a3 += b2[e * 5 + 3]; a4 += b2[e * 5 + 4];
  out[(b << 14) + p] = a0;                         // hm
  out[131072 + ((b * 2 + 0) << 14) + p] = a1;      // wh c0
  out[131072 + ((b * 2 + 1) << 14) + p] = a2;      // wh c1
  out[393216 + ((b * 2 + 0) << 14) + p] = a3;      // reg c0
  out[393216 + ((b * 2 + 1) << 14) + p] = a4;      // reg c1
}

extern "C" void kernel_launch(void* const* d_in, const int* in_sizes, int n_in,
                              void* d_out, int out_size, void* d_ws, size_t ws_size,
                              hipStream_t stream) {
  const float* x          = (const float*)d_in[0];
  const float* g_conv_w   = (const float*)d_in[1];
  const float* g_bn_gamma = (const float*)d_in[2];
  const float* g_bn_beta  = (const float*)d_in[3];
  const float* g_bn_mean  = (const float*)d_in[4];
  const float* g_bn_var   = (const float*)d_in[5];
  const float* g_fc_w     = (const float*)d_in[6];
  const float* g_fc_b     = (const float*)d_in[7];
  const float* e_conv1_w  = (const float*)d_in[8];
  const float* e_conv2_w  = (const float*)d_in[9];
  const float* e_head_w1  = (const float*)d_in[10];
  const float* e_head_b1  = (const float*)d_in[11];
  const float* e_head_w2  = (const float*)d_in[12];
  const float* e_head_b2  = (const float*)d_in[13];
  float* out = (float*)d_out;

  // workspace layout (needs ~201.3 MB)
  float* buf1   = (float*)d_ws;          // 8*64*256*256  = 33,554,432 f (also reused for head1 out)
  float* buf2   = buf1 + 33554432;       // 8*128*128*128 = 16,777,216 f
  float* pooled = buf2 + 16777216;       // 512 f
  int*   sel    = (int*)(pooled + 512);  // 8 ints

  // gating path
  conv7_k<0><<<4096, 256, 0, stream>>>(x, g_conv_w, g_bn_gamma, g_bn_beta,
                                       g_bn_mean, g_bn_var, nullptr, buf1);
  pool_mean_k<<<512, 256, 0, stream>>>(buf1, pooled);
  gate_k<<<1, 64, 0, stream>>>(pooled, g_fc_w, g_fc_b, sel, out + 655360);

  // selected-expert path (top-1 => weight 1.0, single expert per batch item)
  conv7_k<1><<<4096, 256, 0, stream>>>(x, e_conv1_w, nullptr, nullptr,
                                       nullptr, nullptr, sel, buf1);
  conv3_k<2, 64, 256, 128, false><<<1024, 256, 0, stream>>>(buf1, e_conv2_w, nullptr, sel, buf2);
  conv3_k<1, 128, 128, 128, true><<<1024, 256, 0, stream>>>(buf2, e_head_w1, e_head_b1, sel, buf1);
  head2_k<<<512, 256, 0, stream>>>(buf1, e_head_w2, e_head_b2, sel, out);
}